// Round 2
// baseline (9260.277 us; speedup 1.0000x reference)
//
#include <hip/hip_runtime.h>
#include <hip/hip_bf16.h>
#include <stdint.h>

#define B_ 4
#define T_ 2048
#define C_ 2048
#define H_ 16
#define HKV_ 4
#define D_ 128
#define KV_ 512

typedef __attribute__((ext_vector_type(8))) short bf16x8;
typedef __attribute__((ext_vector_type(4))) float f32x4;

__device__ __forceinline__ float bfbits2f(unsigned short u) {
    union { unsigned int u32; float f; } c;
    c.u32 = ((unsigned int)u) << 16;
    return c.f;
}

__device__ __forceinline__ unsigned short f2bf(float f) {
    union { float f; unsigned int u; } c;
    c.f = f;
    unsigned int u = c.u;
    u += 0x7FFFu + ((u >> 16) & 1u);  // RNE
    return (unsigned short)(u >> 16);
}

// ---------------------------------------------------------------------------
// fp32 -> bf16 conversion, 4 elems/thread (float4 in, ushort4 out)
// ---------------------------------------------------------------------------
__global__ __launch_bounds__(256)
void f32_to_bf16(const float* __restrict__ src, unsigned short* __restrict__ dst, int n4)
{
    int i = blockIdx.x * 256 + threadIdx.x;
    if (i < n4) {
        float4 v = ((const float4*)src)[i];
        ushort4 o;
        o.x = f2bf(v.x); o.y = f2bf(v.y); o.z = f2bf(v.z); o.w = f2bf(v.w);
        ((ushort4*)dst)[i] = o;
    }
}

// ---------------------------------------------------------------------------
// bt-GEMM: Cmat[M,N] = A[M,K] @ W[N,K]^T + bias[N]   (bf16 in, fp32 acc,
// OutT out). 128x128 tile / 256 threads (4 waves, each 64x64 = 4x4 MFMA),
// BK=32, global_load_lds width-16 staging (m97 pattern).
// ---------------------------------------------------------------------------
template <typename OutT>
__global__ __launch_bounds__(256)
void gemm_bt_bias(const __hip_bfloat16* __restrict__ A,
                  const __hip_bfloat16* __restrict__ W,
                  const float* __restrict__ bias,
                  OutT* __restrict__ Cmat,
                  int M, int N, int K)
{
    __shared__ __align__(16) __hip_bfloat16 lA[128 * 32];
    __shared__ __align__(16) __hip_bfloat16 lB[128 * 32];

    const int tid  = threadIdx.x;
    const int wave = tid >> 6;
    const int lane = tid & 63;
    const int m0 = blockIdx.x * 128;
    const int n0 = blockIdx.y * 128;
    const int wm = (wave >> 1) * 64;   // wave's M quadrant
    const int wn = (wave & 1) * 64;    // wave's N quadrant
    const int srow = lane >> 2;        // staging: row within 16-row group
    const int scol = (lane & 3) * 8;   // staging: 8-elem (16 B) chunk
    const int quad = lane >> 4;        // 0..3
    const int r16  = lane & 15;

    f32x4 acc[4][4];
#pragma unroll
    for (int i = 0; i < 4; ++i)
#pragma unroll
        for (int j = 0; j < 4; ++j)
            acc[i][j] = (f32x4){0.f, 0.f, 0.f, 0.f};

    const __hip_bfloat16* gA = A + (size_t)(m0 + wave * 16 + srow) * K + scol;
    const __hip_bfloat16* gB = W + (size_t)(n0 + wave * 16 + srow) * K + scol;

    for (int k0 = 0; k0 < K; k0 += 32) {
        __builtin_amdgcn_global_load_lds(
            (const __attribute__((address_space(1))) void*)(gA + k0),
            (__attribute__((address_space(3))) void*)(lA + wave * 16 * 32), 16, 0, 0);
        __builtin_amdgcn_global_load_lds(
            (const __attribute__((address_space(1))) void*)(gA + (size_t)64 * K + k0),
            (__attribute__((address_space(3))) void*)(lA + (64 + wave * 16) * 32), 16, 0, 0);
        __builtin_amdgcn_global_load_lds(
            (const __attribute__((address_space(1))) void*)(gB + k0),
            (__attribute__((address_space(3))) void*)(lB + wave * 16 * 32), 16, 0, 0);
        __builtin_amdgcn_global_load_lds(
            (const __attribute__((address_space(1))) void*)(gB + (size_t)64 * K + k0),
            (__attribute__((address_space(3))) void*)(lB + (64 + wave * 16) * 32), 16, 0, 0);
        __syncthreads();

        bf16x8 af[4], bfr[4];
#pragma unroll
        for (int i = 0; i < 4; ++i)
            af[i] = *(const bf16x8*)(lA + (wm + i * 16 + r16) * 32 + quad * 8);
#pragma unroll
        for (int j = 0; j < 4; ++j)
            bfr[j] = *(const bf16x8*)(lB + (wn + j * 16 + r16) * 32 + quad * 8);
#pragma unroll
        for (int i = 0; i < 4; ++i)
#pragma unroll
            for (int j = 0; j < 4; ++j)
                acc[i][j] = __builtin_amdgcn_mfma_f32_16x16x32_bf16(
                    af[i], bfr[j], acc[i][j], 0, 0, 0);
        __syncthreads();
    }

    // epilogue: C/D layout col=lane&15, row=(lane>>4)*4+reg  [m89/m91]
#pragma unroll
    for (int i = 0; i < 4; ++i) {
        const int row = m0 + wm + i * 16 + quad * 4;
#pragma unroll
        for (int j = 0; j < 4; ++j) {
            const int col = n0 + wn + j * 16 + r16;
            const float bb = bias[col];
#pragma unroll
            for (int r = 0; r < 4; ++r) {
                const float v = acc[i][j][r] + bb;
                if constexpr (sizeof(OutT) == 4) {
                    Cmat[(size_t)(row + r) * N + col] = v;
                } else {
                    ((unsigned short*)Cmat)[(size_t)(row + r) * N + col] = f2bf(v);
                }
            }
        }
    }
}

// ---------------------------------------------------------------------------
// Naive-but-correct GQA causal attention, one wave per query row.
// xq [B,T,C] (head h at channel h*D), xk/xv [B,T,KV] (kv head at hkv*D),
// out xo [B,T,C] bf16. Online softmax, fp32 accum, lanes over d (2/lane).
// ---------------------------------------------------------------------------
__global__ __launch_bounds__(256)
void attn_naive(const __hip_bfloat16* __restrict__ xq,
                const __hip_bfloat16* __restrict__ xk,
                const __hip_bfloat16* __restrict__ xv,
                __hip_bfloat16* __restrict__ xo)
{
    const int wave = threadIdx.x >> 6;
    const int lane = threadIdx.x & 63;
    const int t = blockIdx.x * 4 + wave;
    const int h = blockIdx.y;
    const int b = blockIdx.z;
    const int hkv = h & (HKV_ - 1);              // kv head = h % HKV
    const float scale = 0.08838834764831845f;    // 1/sqrt(128)

    const ushort2* q2 = (const ushort2*)(xq + ((size_t)(b * T_ + t)) * C_ + (size_t)h * D_);
    const ushort2* Kb = (const ushort2*)(xk + ((size_t)b * T_) * KV_ + (size_t)hkv * D_);
    const ushort2* Vb = (const ushort2*)(xv + ((size_t)b * T_) * KV_ + (size_t)hkv * D_);
    const int rs = KV_ / 2;  // row stride in ushort2 units = 256

    ushort2 qq = q2[lane];
    const float q0 = bfbits2f(qq.x);
    const float q1 = bfbits2f(qq.y);

    float m = -3.0e38f, l = 0.f, o0 = 0.f, o1 = 0.f;
    const int send = t + 1;
    int s = 0;
    for (; s + 4 <= send; s += 4) {
        float part[4];
#pragma unroll
        for (int u = 0; u < 4; ++u) {
            ushort2 kk = Kb[(size_t)(s + u) * rs + lane];
            part[u] = q0 * bfbits2f(kk.x) + q1 * bfbits2f(kk.y);
        }
#pragma unroll
        for (int off = 32; off; off >>= 1) {
#pragma unroll
            for (int u = 0; u < 4; ++u) part[u] += __shfl_xor(part[u], off);
        }
#pragma unroll
        for (int u = 0; u < 4; ++u) {
            const float score = part[u] * scale;
            const float mn = fmaxf(m, score);
            const float corr = __expf(m - mn);
            const float p = __expf(score - mn);
            ushort2 vv = Vb[(size_t)(s + u) * rs + lane];
            o0 = o0 * corr + p * bfbits2f(vv.x);
            o1 = o1 * corr + p * bfbits2f(vv.y);
            l = l * corr + p;
            m = mn;
        }
    }
    for (; s < send; ++s) {
        ushort2 kk = Kb[(size_t)s * rs + lane];
        float part = q0 * bfbits2f(kk.x) + q1 * bfbits2f(kk.y);
#pragma unroll
        for (int off = 32; off; off >>= 1) part += __shfl_xor(part, off);
        const float score = part * scale;
        const float mn = fmaxf(m, score);
        const float corr = __expf(m - mn);
        const float p = __expf(score - mn);
        ushort2 vv = Vb[(size_t)s * rs + lane];
        o0 = o0 * corr + p * bfbits2f(vv.x);
        o1 = o1 * corr + p * bfbits2f(vv.y);
        l = l * corr + p;
        m = mn;
    }

    const float inv_l = 1.0f / l;
    __hip_bfloat16* outp = xo + ((size_t)(b * T_ + t)) * C_ + (size_t)h * D_;
    ((unsigned short*)outp)[2 * lane]     = f2bf(o0 * inv_l);
    ((unsigned short*)outp)[2 * lane + 1] = f2bf(o1 * inv_l);
}

// ---------------------------------------------------------------------------
extern "C" void kernel_launch(void* const* d_in, const int* in_sizes, int n_in,
                              void* d_out, int out_size, void* d_ws, size_t ws_size,
                              hipStream_t stream)
{
    const float* query = (const float*)d_in[0];
    const float* key   = (const float*)d_in[1];
    const float* value = (const float*)d_in[2];
    const float* ipw   = (const float*)d_in[3];  // [3072,2048]
    const float* ipb   = (const float*)d_in[4];  // [3072]
    const float* opw   = (const float*)d_in[5];  // [2048,2048]
    const float* opb   = (const float*)d_in[6];  // [2048]
    float* out = (float*)d_out;

    const size_t nQ = (size_t)B_ * T_ * C_;   // 16.78M
    const size_t nW = (size_t)(C_ + 2 * KV_) * C_;  // 6.29M
    const size_t nKV = (size_t)B_ * T_ * KV_; // 4.19M

    // workspace (bf16 elems, 96.5 MB total):
    // qb (act conv, reused for k/v conv and later xo) | wb (weight conv,
    // reused for opw) | xq | xk | xv
    __hip_bfloat16* qb = (__hip_bfloat16*)d_ws;
    __hip_bfloat16* wb = qb + nQ;
    __hip_bfloat16* xq = wb + nW;
    __hip_bfloat16* xk = xq + nQ;
    __hip_bfloat16* xv = xk + nKV;
    __hip_bfloat16* xo = qb;  // alias: qb dead after xv GEMM

    const int M = B_ * T_;  // 8192
    dim3 blk(256);

    // convert weights (once) and query
    f32_to_bf16<<<(int)(nW / 4 / 256), blk, 0, stream>>>(ipw, (unsigned short*)wb, (int)(nW / 4));
    f32_to_bf16<<<(int)(nQ / 4 / 256), blk, 0, stream>>>(query, (unsigned short*)qb, (int)(nQ / 4));
    gemm_bt_bias<__hip_bfloat16><<<dim3(M / 128, C_ / 128), blk, 0, stream>>>(
        qb, wb, ipb, xq, M, C_, C_);

    f32_to_bf16<<<(int)(nQ / 4 / 256), blk, 0, stream>>>(key, (unsigned short*)qb, (int)(nQ / 4));
    gemm_bt_bias<__hip_bfloat16><<<dim3(M / 128, KV_ / 128), blk, 0, stream>>>(
        qb, wb + (size_t)C_ * C_, ipb + C_, xk, M, KV_, C_);

    f32_to_bf16<<<(int)(nQ / 4 / 256), blk, 0, stream>>>(value, (unsigned short*)qb, (int)(nQ / 4));
    gemm_bt_bias<__hip_bfloat16><<<dim3(M / 128, KV_ / 128), blk, 0, stream>>>(
        qb, wb + (size_t)(C_ + KV_) * C_, ipb + C_ + KV_, xv, M, KV_, C_);

    // attention (xo aliases qb — value copy dead now)
    attn_naive<<<dim3(T_ / 4, H_, B_), blk, 0, stream>>>(xq, xk, xv, xo);

    // out projection -> fp32 output
    const size_t nOW = (size_t)C_ * C_;
    f32_to_bf16<<<(int)(nOW / 4 / 256), blk, 0, stream>>>(opw, (unsigned short*)wb, (int)(nOW / 4));
    gemm_bt_bias<float><<<dim3(M / 128, C_ / 128), blk, 0, stream>>>(
        xo, wb, opb, out, M, C_, C_);
}

// Round 3
// 927.058 us; speedup vs baseline: 9.9889x; 9.9889x over previous
//
#include <hip/hip_runtime.h>
#include <hip/hip_bf16.h>
#include <stdint.h>

#define B_ 4
#define T_ 2048
#define C_ 2048
#define H_ 16
#define HKV_ 4
#define D_ 128
#define KV_ 512

typedef __attribute__((ext_vector_type(8))) short bf16x8;
typedef __attribute__((ext_vector_type(4))) float f32x4;

__device__ __forceinline__ unsigned short f2bf(float f) {
    union { float f; unsigned int u; } c;
    c.f = f;
    unsigned int u = c.u;
    u += 0x7FFFu + ((u >> 16) & 1u);  // RNE
    return (unsigned short)(u >> 16);
}

// ---------------------------------------------------------------------------
// fp32 -> bf16 conversion, 4 elems/thread
// ---------------------------------------------------------------------------
__global__ __launch_bounds__(256)
void f32_to_bf16(const float* __restrict__ src, unsigned short* __restrict__ dst, int n4)
{
    int i = blockIdx.x * 256 + threadIdx.x;
    if (i < n4) {
        float4 v = ((const float4*)src)[i];
        ushort4 o;
        o.x = f2bf(v.x); o.y = f2bf(v.y); o.z = f2bf(v.z); o.w = f2bf(v.w);
        ((ushort4*)dst)[i] = o;
    }
}

// ---------------------------------------------------------------------------
// bt-GEMM: Cmat[M,N] = A[M,K] @ W[N,K]^T + bias[N]   (bf16 in, fp32 acc).
// TRANS=true writes output as [B][N][T] (for V^T), t = row % T_.
// ---------------------------------------------------------------------------
template <typename OutT, bool TRANS>
__global__ __launch_bounds__(256)
void gemm_bt_bias(const __hip_bfloat16* __restrict__ A,
                  const __hip_bfloat16* __restrict__ W,
                  const float* __restrict__ bias,
                  OutT* __restrict__ Cmat,
                  int M, int N, int K)
{
    __shared__ __align__(16) __hip_bfloat16 lA[128 * 32];
    __shared__ __align__(16) __hip_bfloat16 lB[128 * 32];

    const int tid  = threadIdx.x;
    const int wave = tid >> 6;
    const int lane = tid & 63;
    const int m0 = blockIdx.x * 128;
    const int n0 = blockIdx.y * 128;
    const int wm = (wave >> 1) * 64;
    const int wn = (wave & 1) * 64;
    const int srow = lane >> 2;
    const int scol = (lane & 3) * 8;
    const int quad = lane >> 4;
    const int r16  = lane & 15;

    f32x4 acc[4][4];
#pragma unroll
    for (int i = 0; i < 4; ++i)
#pragma unroll
        for (int j = 0; j < 4; ++j)
            acc[i][j] = (f32x4){0.f, 0.f, 0.f, 0.f};

    const __hip_bfloat16* gA = A + (size_t)(m0 + wave * 16 + srow) * K + scol;
    const __hip_bfloat16* gB = W + (size_t)(n0 + wave * 16 + srow) * K + scol;

    for (int k0 = 0; k0 < K; k0 += 32) {
        __builtin_amdgcn_global_load_lds(
            (const __attribute__((address_space(1))) void*)(gA + k0),
            (__attribute__((address_space(3))) void*)(lA + wave * 16 * 32), 16, 0, 0);
        __builtin_amdgcn_global_load_lds(
            (const __attribute__((address_space(1))) void*)(gA + (size_t)64 * K + k0),
            (__attribute__((address_space(3))) void*)(lA + (64 + wave * 16) * 32), 16, 0, 0);
        __builtin_amdgcn_global_load_lds(
            (const __attribute__((address_space(1))) void*)(gB + k0),
            (__attribute__((address_space(3))) void*)(lB + wave * 16 * 32), 16, 0, 0);
        __builtin_amdgcn_global_load_lds(
            (const __attribute__((address_space(1))) void*)(gB + (size_t)64 * K + k0),
            (__attribute__((address_space(3))) void*)(lB + (64 + wave * 16) * 32), 16, 0, 0);
        __syncthreads();

        bf16x8 af[4], bfr[4];
#pragma unroll
        for (int i = 0; i < 4; ++i)
            af[i] = *(const bf16x8*)(lA + (wm + i * 16 + r16) * 32 + quad * 8);
#pragma unroll
        for (int j = 0; j < 4; ++j)
            bfr[j] = *(const bf16x8*)(lB + (wn + j * 16 + r16) * 32 + quad * 8);
#pragma unroll
        for (int i = 0; i < 4; ++i)
#pragma unroll
            for (int j = 0; j < 4; ++j)
                acc[i][j] = __builtin_amdgcn_mfma_f32_16x16x32_bf16(
                    af[i], bfr[j], acc[i][j], 0, 0, 0);
        __syncthreads();
    }

    // epilogue: C/D layout col=lane&15, row=(lane>>4)*4+reg  [m89/m91]
#pragma unroll
    for (int i = 0; i < 4; ++i) {
        const int row = m0 + wm + i * 16 + quad * 4;
#pragma unroll
        for (int j = 0; j < 4; ++j) {
            const int col = n0 + wn + j * 16 + r16;
            const float bb = bias[col];
            if constexpr (TRANS) {
                // V^T store: [B][N][T], 4 consecutive t at fixed col
                const int bb_idx = row >> 11;        // row / T_
                const int t = row & (T_ - 1);
                ushort4 o;
                o.x = f2bf(acc[i][j][0] + bb);
                o.y = f2bf(acc[i][j][1] + bb);
                o.z = f2bf(acc[i][j][2] + bb);
                o.w = f2bf(acc[i][j][3] + bb);
                *(ushort4*)((unsigned short*)Cmat +
                            ((size_t)(bb_idx * N + col)) * T_ + t) = o;
            } else {
#pragma unroll
                for (int r = 0; r < 4; ++r) {
                    const float v = acc[i][j][r] + bb;
                    if constexpr (sizeof(OutT) == 4) {
                        Cmat[(size_t)(row + r) * N + col] = v;
                    } else {
                        ((unsigned short*)Cmat)[(size_t)(row + r) * N + col] = f2bf(v);
                    }
                }
            }
        }
    }
}

// ---------------------------------------------------------------------------
// MFMA flash attention (causal, GQA). Block = 128 Q-rows x one (b,h);
// 4 waves, each owns 32 rows. K/V tiles of 64 staged via global_load_lds.
// xq [B,T,C], xk [B,T,KV], xvT [B,KV,T], xo [B,T,C] (all bf16).
// ---------------------------------------------------------------------------
#define PSTRIDE 88   // lP row stride: 176 B = 16B-aligned rows, 2-way banks

__global__ __launch_bounds__(256)
void attn_flash(const __hip_bfloat16* __restrict__ xq,
                const __hip_bfloat16* __restrict__ xk,
                const __hip_bfloat16* __restrict__ xvT,
                __hip_bfloat16* __restrict__ xo)
{
    __shared__ __align__(16) __hip_bfloat16 lK[64 * 128];        // 16 KB
    __shared__ __align__(16) __hip_bfloat16 lV[128 * 64];        // V^T, 16 KB
    __shared__ __align__(16) __hip_bfloat16 lP[4 * 32 * PSTRIDE];// 22.5 KB

    const int tid  = threadIdx.x;
    const int wave = tid >> 6;
    const int lane = tid & 63;
    const int quad = lane >> 4;
    const int r16  = lane & 15;
    const int q0 = blockIdx.x * 128;
    const int h  = blockIdx.y;
    const int b  = blockIdx.z;
    const int hkv = h & (HKV_ - 1);
    const int r0 = q0 + wave * 32;
    const float scale = 0.08838834764831845f;   // 1/sqrt(128)

    // Q fragments (A-layout): qf[i][kc] = Q[r0+i*16+r16][kc*32+quad*8 .. +7]
    bf16x8 qf[2][4];
#pragma unroll
    for (int i = 0; i < 2; ++i)
#pragma unroll
        for (int kc = 0; kc < 4; ++kc)
            qf[i][kc] = *(const bf16x8*)(
                xq + ((size_t)(b * T_ + r0 + i * 16 + r16)) * C_ +
                h * D_ + kc * 32 + quad * 8);

    f32x4 oacc[2][8];
#pragma unroll
    for (int i = 0; i < 2; ++i)
#pragma unroll
        for (int db = 0; db < 8; ++db)
            oacc[i][db] = (f32x4){0.f, 0.f, 0.f, 0.f};
    float mrow[2][4], lrow[2][4];
#pragma unroll
    for (int i = 0; i < 2; ++i)
#pragma unroll
        for (int r = 0; r < 4; ++r) { mrow[i][r] = -3.0e38f; lrow[i][r] = 0.f; }

    const __hip_bfloat16* kb = xk + ((size_t)b * T_) * KV_ + hkv * D_;
    const __hip_bfloat16* vb = xvT + ((size_t)(b * KV_ + hkv * D_)) * T_;
    __hip_bfloat16* lPw = lP + wave * 32 * PSTRIDE;

    const int krow = wave * 16 + (lane >> 4);   // + q*4 ; col (lane&15)*8
    const int kcol = (lane & 15) * 8;
    const int vrow = wave * 32 + (lane >> 3);   // + q*8 ; col (lane&7)*8
    const int vcol = (lane & 7) * 8;

    const int ntiles = q0 / 64 + 2;
    for (int tile = 0; tile < ntiles; ++tile) {
        const int s0 = tile * 64;
        // stage K [64][128] and V^T [128][64]
#pragma unroll
        for (int q = 0; q < 4; ++q) {
            __builtin_amdgcn_global_load_lds(
                (const __attribute__((address_space(1))) void*)(
                    kb + (size_t)(s0 + krow + q * 4) * KV_ + kcol),
                (__attribute__((address_space(3))) void*)(lK + (wave * 16 + q * 4) * 128),
                16, 0, 0);
            __builtin_amdgcn_global_load_lds(
                (const __attribute__((address_space(1))) void*)(
                    vb + (size_t)(vrow + q * 8) * T_ + s0 + vcol),
                (__attribute__((address_space(3))) void*)(lV + (wave * 32 + q * 8) * 64),
                16, 0, 0);
        }
        __syncthreads();

        if (s0 <= r0 + 31) {   // tile intersects this wave's causal region
            const bool diag = (s0 + 63 > r0);

            // ---- QK^T: S[32][64]
            f32x4 sacc[2][4];
#pragma unroll
            for (int i = 0; i < 2; ++i)
#pragma unroll
                for (int j = 0; j < 4; ++j)
                    sacc[i][j] = (f32x4){0.f, 0.f, 0.f, 0.f};
#pragma unroll
            for (int kc = 0; kc < 4; ++kc) {
                bf16x8 kf[4];
#pragma unroll
                for (int j = 0; j < 4; ++j)
                    kf[j] = *(const bf16x8*)(lK + (j * 16 + r16) * 128 + kc * 32 + quad * 8);
#pragma unroll
                for (int i = 0; i < 2; ++i)
#pragma unroll
                    for (int j = 0; j < 4; ++j)
                        sacc[i][j] = __builtin_amdgcn_mfma_f32_16x16x32_bf16(
                            qf[i][kc], kf[j], sacc[i][j], 0, 0, 0);
            }

            // ---- online softmax per 16-row block
#pragma unroll
            for (int i = 0; i < 2; ++i) {
                float sv[4][4];
#pragma unroll
                for (int j = 0; j < 4; ++j)
#pragma unroll
                    for (int r = 0; r < 4; ++r) {
                        float v = sacc[i][j][r] * scale;
                        if (diag) {
                            const int rr = r0 + i * 16 + quad * 4 + r;
                            const int cc = s0 + j * 16 + r16;
                            if (cc > rr) v = -3.0e38f;
                        }
                        sv[j][r] = v;
                    }
                float mx[4];
#pragma unroll
                for (int r = 0; r < 4; ++r)
                    mx[r] = fmaxf(fmaxf(sv[0][r], sv[1][r]), fmaxf(sv[2][r], sv[3][r]));
#pragma unroll
                for (int off = 1; off <= 8; off <<= 1)
#pragma unroll
                    for (int r = 0; r < 4; ++r)
                        mx[r] = fmaxf(mx[r], __shfl_xor(mx[r], off));
                float al[4], rs[4];
#pragma unroll
                for (int r = 0; r < 4; ++r) {
                    const float mn = fmaxf(mrow[i][r], mx[r]);
                    al[r] = __expf(mrow[i][r] - mn);
                    mrow[i][r] = mn;
                    rs[r] = 0.f;
                }
#pragma unroll
                for (int j = 0; j < 4; ++j)
#pragma unroll
                    for (int r = 0; r < 4; ++r) {
                        const float p = __expf(sv[j][r] - mrow[i][r]);
                        sv[j][r] = p;
                        rs[r] += p;
                    }
#pragma unroll
                for (int off = 1; off <= 8; off <<= 1)
#pragma unroll
                    for (int r = 0; r < 4; ++r)
                        rs[r] += __shfl_xor(rs[r], off);
#pragma unroll
                for (int r = 0; r < 4; ++r)
                    lrow[i][r] = lrow[i][r] * al[r] + rs[r];
#pragma unroll
                for (int db = 0; db < 8; ++db)
#pragma unroll
                    for (int r = 0; r < 4; ++r)
                        oacc[i][db][r] *= al[r];
                // P -> LDS (C-layout write): row i*16+quad*4+r, col j*16+r16
#pragma unroll
                for (int j = 0; j < 4; ++j)
#pragma unroll
                    for (int r = 0; r < 4; ++r)
                        ((unsigned short*)lPw)[(i * 16 + quad * 4 + r) * PSTRIDE +
                                               j * 16 + r16] = f2bf(sv[j][r]);
            }

            // ---- PV: O += P[32][64] @ V[64][128]
#pragma unroll
            for (int sc = 0; sc < 2; ++sc) {
                bf16x8 pf[2];
#pragma unroll
                for (int i = 0; i < 2; ++i)
                    pf[i] = *(const bf16x8*)(lPw + (i * 16 + r16) * PSTRIDE +
                                             sc * 32 + quad * 8);
#pragma unroll
                for (int db = 0; db < 8; ++db) {
                    const bf16x8 vf = *(const bf16x8*)(lV + (db * 16 + r16) * 64 +
                                                       sc * 32 + quad * 8);
#pragma unroll
                    for (int i = 0; i < 2; ++i)
                        oacc[i][db] = __builtin_amdgcn_mfma_f32_16x16x32_bf16(
                            pf[i], vf, oacc[i][db], 0, 0, 0);
                }
            }
        }
        __syncthreads();
    }

    // epilogue: O / l -> xo (C-layout rows)
#pragma unroll
    for (int i = 0; i < 2; ++i) {
        float inv[4];
#pragma unroll
        for (int r = 0; r < 4; ++r) inv[r] = 1.0f / lrow[i][r];
#pragma unroll
        for (int db = 0; db < 8; ++db)
#pragma unroll
            for (int r = 0; r < 4; ++r)
                ((unsigned short*)xo)[((size_t)(b * T_ + r0 + i * 16 + quad * 4 + r)) * C_ +
                                      h * D_ + db * 16 + r16] =
                    f2bf(oacc[i][db][r] * inv[r]);
    }
}

// ---------------------------------------------------------------------------
extern "C" void kernel_launch(void* const* d_in, const int* in_sizes, int n_in,
                              void* d_out, int out_size, void* d_ws, size_t ws_size,
                              hipStream_t stream)
{
    const float* query = (const float*)d_in[0];
    const float* key   = (const float*)d_in[1];
    const float* value = (const float*)d_in[2];
    const float* ipw   = (const float*)d_in[3];  // [3072,2048]
    const float* ipb   = (const float*)d_in[4];  // [3072]
    const float* opw   = (const float*)d_in[5];  // [2048,2048]
    const float* opb   = (const float*)d_in[6];  // [2048]
    float* out = (float*)d_out;

    const size_t nQ  = (size_t)B_ * T_ * C_;          // 16.78M
    const size_t nW  = (size_t)(C_ + 2 * KV_) * C_;   // 6.29M
    const size_t nKV = (size_t)B_ * T_ * KV_;         // 4.19M

    __hip_bfloat16* qb  = (__hip_bfloat16*)d_ws;
    __hip_bfloat16* wb  = qb + nQ;
    __hip_bfloat16* xq  = wb + nW;
    __hip_bfloat16* xk  = xq + nQ;
    __hip_bfloat16* xvT = xk + nKV;
    __hip_bfloat16* xo  = qb;  // alias: qb dead after V GEMM

    const int M = B_ * T_;  // 8192
    dim3 blk(256);

    f32_to_bf16<<<(int)(nW / 4 / 256), blk, 0, stream>>>(ipw, (unsigned short*)wb, (int)(nW / 4));
    f32_to_bf16<<<(int)(nQ / 4 / 256), blk, 0, stream>>>(query, (unsigned short*)qb, (int)(nQ / 4));
    gemm_bt_bias<__hip_bfloat16, false><<<dim3(M / 128, C_ / 128), blk, 0, stream>>>(
        qb, wb, ipb, xq, M, C_, C_);

    f32_to_bf16<<<(int)(nQ / 4 / 256), blk, 0, stream>>>(key, (unsigned short*)qb, (int)(nQ / 4));
    gemm_bt_bias<__hip_bfloat16, false><<<dim3(M / 128, KV_ / 128), blk, 0, stream>>>(
        qb, wb + (size_t)C_ * C_, ipb + C_, xk, M, KV_, C_);

    f32_to_bf16<<<(int)(nQ / 4 / 256), blk, 0, stream>>>(value, (unsigned short*)qb, (int)(nQ / 4));
    gemm_bt_bias<__hip_bfloat16, true><<<dim3(M / 128, KV_ / 128), blk, 0, stream>>>(
        qb, wb + (size_t)(C_ + KV_) * C_, ipb + C_ + KV_, xvT, M, KV_, C_);

    attn_flash<<<dim3(T_ / 128, H_, B_), blk, 0, stream>>>(xq, xk, xvT, xo);

    const size_t nOW = (size_t)C_ * C_;
    f32_to_bf16<<<(int)(nOW / 4 / 256), blk, 0, stream>>>(opw, (unsigned short*)wb, (int)(nOW / 4));
    gemm_bt_bias<float, false><<<dim3(M / 128, C_ / 128), blk, 0, stream>>>(
        xo, wb, opb, out, M, C_, C_);
}